// Round 4
// baseline (1189.088 us; speedup 1.0000x reference)
//
#include <hip/hip_runtime.h>
#include <hip/hip_bf16.h>

// Problem constants (fixed by the reference file).
#define K_OFF 27
#define M_PTS 100000
#define KM (K_OFF * M_PTS)      // 2,700,000 contributions
#define C_CH 64
#define N_OUT_PTS 400000
#define BN_EPS 1e-5f
#define N_TILES (N_OUT_PTS / 16)   // 25000 output tiles of 16 rows

typedef __attribute__((ext_vector_type(8))) short short8;  // 8 bf16 = 4 VGPRs
typedef __attribute__((ext_vector_type(4))) float f32x4;

__device__ inline short bf16c(float f) {
    return __builtin_bit_cast(short, __float2bfloat16(f));
}

// Packed 2xbf16 atomic add (fallback path only).
__device__ inline void pk_atomic_add_bf16(__hip_bfloat16* p, int bits) {
#if __has_builtin(__builtin_amdgcn_global_atomic_fadd_v2bf16)
    typedef short s2v __attribute__((ext_vector_type(2)));
    typedef __attribute__((address_space(1))) s2v* gp;
    s2v v;
    __builtin_memcpy(&v, &bits, 4);
    __builtin_amdgcn_global_atomic_fadd_v2bf16((gp)(unsigned long long)p, v);
#else
    asm volatile("global_atomic_pk_add_bf16 %0, %1, off"
                 :: "v"((unsigned long long)p), "v"(bits) : "memory");
#endif
}

__device__ inline unsigned bytesum(unsigned v) {
    return (v & 255u) + ((v >> 8) & 255u) + ((v >> 16) & 255u) + (v >> 24);
}

// ===========================================================================
// CSR construction: per-(row,k) byte-packed histogram -> scan -> k-sorted fill
// hist/cursor layout: 8 uints per row; byte j of word w = count for k=4w+j.
// ===========================================================================

__global__ __launch_bounds__(256) void hist_kernel(
    const int* __restrict__ out_idx, unsigned* __restrict__ hist)
{
    int i = blockIdx.x * 256 + threadIdx.x;
    if (i >= KM) return;
    int row = out_idx[i];
    int k = i / M_PTS;
    atomicAdd(&hist[(size_t)row * 8 + (k >> 2)], 1u << (8 * (k & 3)));
}

// Per-1024-row block scan of row totals (derived by byte-summing hist).
__global__ __launch_bounds__(256) void scan_a(
    const unsigned* __restrict__ hist, int* __restrict__ partial,
    int* __restrict__ blockSums)
{
    __shared__ int sh[256];
    const int t = threadIdx.x, b = blockIdx.x;
    const int r0 = b * 1024 + t * 4;
    int cnt[4] = {0, 0, 0, 0};
    if (r0 < N_OUT_PTS) {
        #pragma unroll
        for (int u = 0; u < 4; ++u) {
            const uint4* hp = (const uint4*)(hist + (size_t)(r0 + u) * 8);
            uint4 a = hp[0], bq = hp[1];
            cnt[u] = (int)(bytesum(a.x) + bytesum(a.y) + bytesum(a.z) + bytesum(a.w) +
                           bytesum(bq.x) + bytesum(bq.y) + bytesum(bq.z) + bytesum(bq.w));
        }
    }
    int tsum = cnt[0] + cnt[1] + cnt[2] + cnt[3];
    sh[t] = tsum;
    __syncthreads();
    for (int o = 1; o < 256; o <<= 1) {
        int u = (t >= o) ? sh[t - o] : 0;
        __syncthreads();
        sh[t] += u;
        __syncthreads();
    }
    int excl = sh[t] - tsum;
    if (r0 < N_OUT_PTS) {
        partial[r0]     = excl;
        partial[r0 + 1] = excl + cnt[0];
        partial[r0 + 2] = excl + cnt[0] + cnt[1];
        partial[r0 + 3] = excl + cnt[0] + cnt[1] + cnt[2];
    }
    if (t == 255) blockSums[b] = sh[255];
}

#define SCAN_BLOCKS ((N_OUT_PTS + 1023) / 1024)   // 391

__global__ __launch_bounds__(512) void scan_b(
    const int* __restrict__ blockSums, int* __restrict__ blockOff)
{
    __shared__ int sh[512];
    const int t = threadIdx.x;
    int v = (t < SCAN_BLOCKS) ? blockSums[t] : 0;
    sh[t] = v;
    __syncthreads();
    for (int o = 1; o < 512; o <<= 1) {
        int u = (t >= o) ? sh[t - o] : 0;
        __syncthreads();
        sh[t] += u;
        __syncthreads();
    }
    if (t < SCAN_BLOCKS) blockOff[t] = sh[t] - v;
}

// Place each contribution at row_start + (#entries of row with k'<k) + seq-in-k.
__global__ __launch_bounds__(256) void fill_kernel(
    const int* __restrict__ out_idx, const int* __restrict__ in_idx,
    const unsigned* __restrict__ hist, unsigned* __restrict__ cursor,
    const int* __restrict__ partial, const int* __restrict__ blockOff,
    int* __restrict__ entries)
{
    int i = blockIdx.x * 256 + threadIdx.x;
    if (i >= KM) return;
    int row = out_idx[i];
    int k = i / M_PTS;
    const unsigned* hw = hist + (size_t)row * 8;
    int w = k >> 2, r = k & 3;
    int pre = 0;
    for (int q = 0; q < w; ++q) pre += (int)bytesum(hw[q]);
    unsigned v = hw[w];
    for (int b = 0; b < r; ++b) pre += (int)((v >> (8 * b)) & 255u);
    unsigned old = atomicAdd(&cursor[(size_t)row * 8 + w], 1u << (8 * r));
    int inK = (int)((old >> (8 * r)) & 255u);
    int pos = partial[row] + blockOff[row >> 10] + pre + inK;
    entries[pos] = in_idx[i];
}

// Prepack W into per-lane MFMA B-fragment layout: packedB[k][lane][s*4+tt][j],
// element j = bf16(W[k][32s+8g+j][4c+tt]). 221 KB, L2-resident.
__global__ __launch_bounds__(64) void prepack_B(
    const float* __restrict__ W, unsigned short* __restrict__ packedB)
{
    const int k = blockIdx.x;
    const int lane = threadIdx.x;
    const int g = lane >> 4, c = lane & 15;
    const float* __restrict__ Wk = W + (size_t)k * C_CH * C_CH;
    #pragma unroll
    for (int s = 0; s < 2; ++s) {
        #pragma unroll
        for (int tt = 0; tt < 4; ++tt) {
            short8 v;
            #pragma unroll
            for (int j = 0; j < 8; ++j)
                v[j] = bf16c(Wk[(size_t)(32 * s + 8 * g + j) * C_CH + 4 * c + tt]);
            *(short8*)(packedB + ((size_t)(k * 64 + lane)) * 64 + (s * 4 + tt) * 8) = v;
        }
    }
}

// ===========================================================================
// Output-stationary fused gather-GEMM-BNstats. One wave = 2 tiles of 16 rows.
// Lane (g=lane>>4, c=lane&15): gather-role row = tile*16+c (A-row c, cin
// slice 8g); write-role rows = tile*16+4g+e, couts 4c+tt (validated D layout).
// Per k (wave-uniform): load bfrag; while(__any(j<r)) rounds consume each
// row's k-sorted entry stream with 1-deep register prefetch; fp32 acc in regs
// across all 27 k -> single coalesced preact write + fused BN stats.
// ===========================================================================
__global__ __launch_bounds__(256) void gather_bn_fused(
    const float* __restrict__ x, const unsigned short* __restrict__ packedB,
    const int* __restrict__ entries, const int* __restrict__ partial,
    const int* __restrict__ blockOff, const unsigned* __restrict__ hist,
    float* __restrict__ preact, float* __restrict__ stats)
{
    const int lane = threadIdx.x & 63;
    const int wave = threadIdx.x >> 6;
    const int g = lane >> 4, c = lane & 15;
    const int gw = blockIdx.x * 4 + wave;          // 0..12499
    const int tileA = 2 * gw, tileB = 2 * gw + 1;  // 0..24999
    const int rowA = tileA * 16 + c;
    const int rowB = tileB * 16 + c;

    int ptrA = partial[rowA] + blockOff[rowA >> 10];
    int ptrB = partial[rowB] + blockOff[rowB >> 10];

    // 1-deep stream prefetch. entries[] has a zeroed 64-int pad past KM, and
    // the initial indices are clamped, so overrun reads are always safe.
    float4 nxA[4], nxB[4];
    {
        int iA = ptrA < KM ? ptrA : KM;
        int iB = ptrB < KM ? ptrB : KM;
        int sA = entries[iA];
        const float4* xr = (const float4*)x + (size_t)sA * 16;
        nxA[0] = xr[2 * g];     nxA[1] = xr[2 * g + 1];
        nxA[2] = xr[8 + 2 * g]; nxA[3] = xr[8 + 2 * g + 1];
        int sB = entries[iB];
        const float4* xs = (const float4*)x + (size_t)sB * 16;
        nxB[0] = xs[2 * g];     nxB[1] = xs[2 * g + 1];
        nxB[2] = xs[8 + 2 * g]; nxB[3] = xs[8 + 2 * g + 1];
    }

    f32x4 accA[4], accB[4];
    #pragma unroll
    for (int tt = 0; tt < 4; ++tt) {
        accA[tt] = (f32x4){0.f, 0.f, 0.f, 0.f};
        accB[tt] = (f32x4){0.f, 0.f, 0.f, 0.f};
    }

    for (int k = 0; k < K_OFF; ++k) {
        short8 bfrag[8];   // [s*4+tt]
        {
            const short8* bp = (const short8*)packedB + (size_t)(k * 64 + lane) * 8;
            #pragma unroll
            for (int f = 0; f < 8; ++f) bfrag[f] = bp[f];
        }
        const int sh8 = 8 * (k & 3);
        int rA = (int)((hist[(size_t)rowA * 8 + (k >> 2)] >> sh8) & 255u);
        int rB = (int)((hist[(size_t)rowB * 8 + (k >> 2)] >> sh8) & 255u);

        int j = 0;
        while (__any(j < rA)) {
            bool act = j < rA;
            short8 af0 = {0, 0, 0, 0, 0, 0, 0, 0};
            short8 af1 = {0, 0, 0, 0, 0, 0, 0, 0};
            if (act) {
                #pragma unroll
                for (int q = 0; q < 4; ++q) {
                    af0[q]     = bf16c(nxA[0][q]);
                    af0[q + 4] = bf16c(nxA[1][q]);
                    af1[q]     = bf16c(nxA[2][q]);
                    af1[q + 4] = bf16c(nxA[3][q]);
                }
                ++ptrA;
                int s_ = entries[ptrA];
                const float4* xr = (const float4*)x + (size_t)s_ * 16;
                nxA[0] = xr[2 * g];     nxA[1] = xr[2 * g + 1];
                nxA[2] = xr[8 + 2 * g]; nxA[3] = xr[8 + 2 * g + 1];
            }
            #pragma unroll
            for (int tt = 0; tt < 4; ++tt) {
                f32x4 z = __builtin_amdgcn_mfma_f32_16x16x32_bf16(af0, bfrag[tt], accA[tt], 0, 0, 0);
                accA[tt] = __builtin_amdgcn_mfma_f32_16x16x32_bf16(af1, bfrag[4 + tt], z, 0, 0, 0);
            }
            ++j;
        }
        j = 0;
        while (__any(j < rB)) {
            bool act = j < rB;
            short8 af0 = {0, 0, 0, 0, 0, 0, 0, 0};
            short8 af1 = {0, 0, 0, 0, 0, 0, 0, 0};
            if (act) {
                #pragma unroll
                for (int q = 0; q < 4; ++q) {
                    af0[q]     = bf16c(nxB[0][q]);
                    af0[q + 4] = bf16c(nxB[1][q]);
                    af1[q]     = bf16c(nxB[2][q]);
                    af1[q + 4] = bf16c(nxB[3][q]);
                }
                ++ptrB;
                int s_ = entries[ptrB];
                const float4* xs = (const float4*)x + (size_t)s_ * 16;
                nxB[0] = xs[2 * g];     nxB[1] = xs[2 * g + 1];
                nxB[2] = xs[8 + 2 * g]; nxB[3] = xs[8 + 2 * g + 1];
            }
            #pragma unroll
            for (int tt = 0; tt < 4; ++tt) {
                f32x4 z = __builtin_amdgcn_mfma_f32_16x16x32_bf16(af0, bfrag[tt], accB[tt], 0, 0, 0);
                accB[tt] = __builtin_amdgcn_mfma_f32_16x16x32_bf16(af1, bfrag[4 + tt], z, 0, 0, 0);
            }
            ++j;
        }
    }

    // Epilogue: coalesced preact writes + per-lane BN partial sums.
    float s[4] = {0.f, 0.f, 0.f, 0.f}, q[4] = {0.f, 0.f, 0.f, 0.f};
    #pragma unroll
    for (int e = 0; e < 4; ++e) {
        float4 w;
        w.x = accA[0][e]; w.y = accA[1][e]; w.z = accA[2][e]; w.w = accA[3][e];
        *(float4*)(preact + (size_t)(tileA * 16 + 4 * g + e) * C_CH + 4 * c) = w;
        s[0] += w.x; s[1] += w.y; s[2] += w.z; s[3] += w.w;
        q[0] += w.x * w.x; q[1] += w.y * w.y; q[2] += w.z * w.z; q[3] += w.w * w.w;
        float4 u;
        u.x = accB[0][e]; u.y = accB[1][e]; u.z = accB[2][e]; u.w = accB[3][e];
        *(float4*)(preact + (size_t)(tileB * 16 + 4 * g + e) * C_CH + 4 * c) = u;
        s[0] += u.x; s[1] += u.y; s[2] += u.z; s[3] += u.w;
        q[0] += u.x * u.x; q[1] += u.y * u.y; q[2] += u.z * u.z; q[3] += u.w * u.w;
    }

    __shared__ float sh[2][256][4];
    #pragma unroll
    for (int tt = 0; tt < 4; ++tt) {
        sh[0][threadIdx.x][tt] = s[tt];
        sh[1][threadIdx.x][tt] = q[tt];
    }
    __syncthreads();
    if (threadIdx.x < C_CH) {
        const int ch = threadIdx.x;
        const int cc = ch >> 2, jj = ch & 3;
        float ts = 0.f, tq = 0.f;
        #pragma unroll
        for (int u = 0; u < 16; ++u) {
            ts += sh[0][16 * u + cc][jj];
            tq += sh[1][16 * u + cc][jj];
        }
        unsafeAtomicAdd(&stats[ch], ts);
        unsafeAtomicAdd(&stats[C_CH + ch], tq);
    }
}

// In-place BN+ReLU on fp32 preact (= d_out).
__global__ __launch_bounds__(256) void bn_apply_f32(
    float* __restrict__ out, const float* __restrict__ stats,
    const float* __restrict__ gamma, const float* __restrict__ beta)
{
    const float inv_n = 1.0f / (float)N_OUT_PTS;
    const int c0 = 8 * (threadIdx.x & 7);
    float sc[8], bs[8];
    #pragma unroll
    for (int j = 0; j < 8; ++j) {
        int ch = c0 + j;
        float mean = stats[ch] * inv_n;
        float var = stats[C_CH + ch] * inv_n - mean * mean;
        float sfac = gamma[ch] * rsqrtf(var + BN_EPS);
        sc[j] = sfac;
        bs[j] = beta[ch] - mean * sfac;
    }
    float4* o4 = (float4*)out;
    const size_t n = (size_t)N_OUT_PTS * C_CH / 8;
    const size_t stride = (size_t)gridDim.x * blockDim.x;
    for (size_t i = (size_t)blockIdx.x * blockDim.x + threadIdx.x; i < n; i += stride) {
        float4 r0 = o4[2 * i], r1 = o4[2 * i + 1];
        r0.x = fmaxf(fmaf(r0.x, sc[0], bs[0]), 0.f);
        r0.y = fmaxf(fmaf(r0.y, sc[1], bs[1]), 0.f);
        r0.z = fmaxf(fmaf(r0.z, sc[2], bs[2]), 0.f);
        r0.w = fmaxf(fmaf(r0.w, sc[3], bs[3]), 0.f);
        r1.x = fmaxf(fmaf(r1.x, sc[4], bs[4]), 0.f);
        r1.y = fmaxf(fmaf(r1.y, sc[5], bs[5]), 0.f);
        r1.z = fmaxf(fmaf(r1.z, sc[6], bs[6]), 0.f);
        r1.w = fmaxf(fmaf(r1.w, sc[7], bs[7]), 0.f);
        o4[2 * i] = r0;
        o4[2 * i + 1] = r1;
    }
}

// ===========================================================================
// FALLBACK (ws implausibly small): round-1 atomic-scatter pipeline, proven.
// ===========================================================================
#define TILE_PTS 16
#define NT (M_PTS / TILE_PTS)
#define FB_BLKX 64
#define FB_WSTRIDE (FB_BLKX * 4)

__device__ __attribute__((always_inline)) inline void load_bfrag_fb(
    const float* __restrict__ Wk, int g, int c, short8 bfrag[2][4])
{
    #pragma unroll
    for (int s = 0; s < 2; ++s) {
        #pragma unroll
        for (int tt = 0; tt < 4; ++tt) {
            short8 v;
            #pragma unroll
            for (int j = 0; j < 8; ++j)
                v[j] = bf16c(Wk[(size_t)(32 * s + 8 * g + j) * C_CH + 4 * c + tt]);
            bfrag[s][tt] = v;
        }
    }
}

__global__ __launch_bounds__(256, 4) void scatter_gemm_fb(
    const float* __restrict__ x, const float* __restrict__ W,
    const int* __restrict__ in_idx, const int* __restrict__ out_idx,
    __hip_bfloat16* __restrict__ out_ws)
{
    const int k = blockIdx.y;
    const int lane = threadIdx.x & 63;
    const int wave = threadIdx.x >> 6;
    const int g = lane >> 4, c = lane & 15;
    short8 bfrag[2][4];
    load_bfrag_fb(W + (size_t)k * C_CH * C_CH, g, c, bfrag);
    const int kbase = k * M_PTS;
    for (int t = blockIdx.x * 4 + wave; t < NT; t += FB_WSTRIDE) {
        int src = in_idx[kbase + t * TILE_PTS + c];
        const float4* xr = (const float4*)x + (size_t)src * 16;
        float4 cur[4];
        cur[0] = xr[2 * g];     cur[1] = xr[2 * g + 1];
        cur[2] = xr[8 + 2 * g]; cur[3] = xr[8 + 2 * g + 1];
        int dstv[4];
        #pragma unroll
        for (int e = 0; e < 4; ++e)
            dstv[e] = out_idx[kbase + t * TILE_PTS + 4 * g + e];
        short8 af0, af1;
        #pragma unroll
        for (int j = 0; j < 4; ++j) {
            af0[j] = bf16c(cur[0][j]); af0[j + 4] = bf16c(cur[1][j]);
            af1[j] = bf16c(cur[2][j]); af1[j + 4] = bf16c(cur[3][j]);
        }
        f32x4 acc[4];
        #pragma unroll
        for (int tt = 0; tt < 4; ++tt) {
            f32x4 z = {0.f, 0.f, 0.f, 0.f};
            z       = __builtin_amdgcn_mfma_f32_16x16x32_bf16(af0, bfrag[0][tt], z, 0, 0, 0);
            acc[tt] = __builtin_amdgcn_mfma_f32_16x16x32_bf16(af1, bfrag[1][tt], z, 0, 0, 0);
        }
        #pragma unroll
        for (int e = 0; e < 4; ++e) {
            __hip_bfloat16* rp = out_ws + (size_t)dstv[e] * C_CH + 4 * c;
            union { __hip_bfloat162 h; int i; } p0, p1;
            p0.h = __hip_bfloat162(__float2bfloat16(acc[0][e]), __float2bfloat16(acc[1][e]));
            p1.h = __hip_bfloat162(__float2bfloat16(acc[2][e]), __float2bfloat16(acc[3][e]));
            pk_atomic_add_bf16(rp, p0.i);
            pk_atomic_add_bf16(rp + 2, p1.i);
        }
    }
}

__global__ __launch_bounds__(256) void bn_stats_fb(
    const __hip_bfloat16* __restrict__ ws, float* __restrict__ stats)
{
    const uint4* in = (const uint4*)ws;
    const size_t n = (size_t)N_OUT_PTS * C_CH / 8;
    const size_t stride = (size_t)gridDim.x * blockDim.x;
    float s[8], s2[8];
    #pragma unroll
    for (int j = 0; j < 8; ++j) { s[j] = 0.f; s2[j] = 0.f; }
    for (size_t i = (size_t)blockIdx.x * blockDim.x + threadIdx.x; i < n; i += stride) {
        uint4 qv = in[i];
        unsigned wds[4] = {qv.x, qv.y, qv.z, qv.w};
        #pragma unroll
        for (int j = 0; j < 4; ++j) {
            __hip_bfloat162 h = *(__hip_bfloat162*)&wds[j];
            float f0 = __low2float(h), f1 = __high2float(h);
            s[2 * j] += f0;  s2[2 * j] += f0 * f0;
            s[2 * j + 1] += f1; s2[2 * j + 1] += f1 * f1;
        }
    }
    __shared__ float sh[2][256][8];
    #pragma unroll
    for (int j = 0; j < 8; ++j) { sh[0][threadIdx.x][j] = s[j]; sh[1][threadIdx.x][j] = s2[j]; }
    __syncthreads();
    if (threadIdx.x < C_CH) {
        const int cch = threadIdx.x;
        float ts = 0.f, t2 = 0.f;
        #pragma unroll
        for (int u = 0; u < 32; ++u) {
            ts += sh[0][8 * u + (cch >> 3)][cch & 7];
            t2 += sh[1][8 * u + (cch >> 3)][cch & 7];
        }
        unsafeAtomicAdd(&stats[cch], ts);
        unsafeAtomicAdd(&stats[C_CH + cch], t2);
    }
}

__global__ __launch_bounds__(256) void bn_apply_fb(
    const __hip_bfloat16* __restrict__ ws, const float* __restrict__ stats,
    const float* __restrict__ gamma, const float* __restrict__ beta,
    float* __restrict__ out)
{
    const float inv_n = 1.0f / (float)N_OUT_PTS;
    const int c0 = 8 * (threadIdx.x & 7);
    float sc[8], bs[8];
    #pragma unroll
    for (int j = 0; j < 8; ++j) {
        int ch = c0 + j;
        float mean = stats[ch] * inv_n;
        float var = stats[C_CH + ch] * inv_n - mean * mean;
        float sfac = gamma[ch] * rsqrtf(var + BN_EPS);
        sc[j] = sfac;
        bs[j] = beta[ch] - mean * sfac;
    }
    const uint4* in = (const uint4*)ws;
    float4* o4 = (float4*)out;
    const size_t n = (size_t)N_OUT_PTS * C_CH / 8;
    const size_t stride = (size_t)gridDim.x * blockDim.x;
    for (size_t i = (size_t)blockIdx.x * blockDim.x + threadIdx.x; i < n; i += stride) {
        uint4 qv = in[i];
        unsigned wds[4] = {qv.x, qv.y, qv.z, qv.w};
        float f[8];
        #pragma unroll
        for (int j = 0; j < 4; ++j) {
            __hip_bfloat162 h = *(__hip_bfloat162*)&wds[j];
            f[2 * j] = __low2float(h);
            f[2 * j + 1] = __high2float(h);
        }
        float4 r0, r1;
        r0.x = fmaxf(fmaf(f[0], sc[0], bs[0]), 0.f);
        r0.y = fmaxf(fmaf(f[1], sc[1], bs[1]), 0.f);
        r0.z = fmaxf(fmaf(f[2], sc[2], bs[2]), 0.f);
        r0.w = fmaxf(fmaf(f[3], sc[3], bs[3]), 0.f);
        r1.x = fmaxf(fmaf(f[4], sc[4], bs[4]), 0.f);
        r1.y = fmaxf(fmaf(f[5], sc[5], bs[5]), 0.f);
        r1.z = fmaxf(fmaf(f[6], sc[6], bs[6]), 0.f);
        r1.w = fmaxf(fmaf(f[7], sc[7], bs[7]), 0.f);
        o4[2 * i] = r0;
        o4[2 * i + 1] = r1;
    }
}

extern "C" void kernel_launch(void* const* d_in, const int* in_sizes, int n_in,
                              void* d_out, int out_size, void* d_ws, size_t ws_size,
                              hipStream_t stream) {
    const float* x      = (const float*)d_in[0];
    const float* W      = (const float*)d_in[1];
    const float* gamma  = (const float*)d_in[2];
    const float* beta   = (const float*)d_in[3];
    const int*   in_idx = (const int*)d_in[4];
    const int*   out_idx= (const int*)d_in[5];
    float* out = (float*)d_out;

    // Workspace layout (~38.3 MB).
    auto al = [](size_t v) { return (v + 255) & ~(size_t)255; };
    size_t off = 0;
    const size_t entries_off = off; off += al((size_t)(KM + 64) * 4);   // +64 pad for prefetch overrun
    const size_t partial_off = off; off += al((size_t)N_OUT_PTS * 4);
    const size_t zero_start  = off;
    const size_t hist_off    = off; off += al((size_t)N_OUT_PTS * 32);
    const size_t cursor_off  = off; off += al((size_t)N_OUT_PTS * 32);
    const size_t bsum_off    = off; off += al(512 * 4);
    const size_t boff_off    = off; off += al(512 * 4);
    const size_t stats_off   = off; off += al(2 * C_CH * sizeof(float));
    const size_t zero_end    = off;
    const size_t packB_off   = off; off += al((size_t)K_OFF * 64 * 128);
    const size_t NEEDED = off;

    if (ws_size >= NEEDED) {
        char* wsb = (char*)d_ws;
        int*      entries = (int*)(wsb + entries_off);
        int*      partial = (int*)(wsb + partial_off);
        unsigned* hist    = (unsigned*)(wsb + hist_off);
        unsigned* cursor  = (unsigned*)(wsb + cursor_off);
        int*      bsum    = (int*)(wsb + bsum_off);
        int*      boff    = (int*)(wsb + boff_off);
        float*    stats   = (float*)(wsb + stats_off);
        unsigned short* packB = (unsigned short*)(wsb + packB_off);

        (void)hipMemsetAsync(wsb + zero_start, 0, zero_end - zero_start, stream);
        // Zero the prefetch pad past entries[KM) — round-3 crash: garbage pad
        // values became OOB x-row addresses (device page fault / abort).
        (void)hipMemsetAsync(entries + KM, 0, 64 * sizeof(int), stream);

        prepack_B<<<K_OFF, 64, 0, stream>>>(W, packB);
        hist_kernel<<<(KM + 255) / 256, 256, 0, stream>>>(out_idx, hist);
        scan_a<<<SCAN_BLOCKS, 256, 0, stream>>>(hist, partial, bsum);
        scan_b<<<1, 512, 0, stream>>>(bsum, boff);
        fill_kernel<<<(KM + 255) / 256, 256, 0, stream>>>(
            out_idx, in_idx, hist, cursor, partial, boff, entries);
        gather_bn_fused<<<N_TILES / 8, 256, 0, stream>>>(
            x, packB, entries, partial, boff, hist, out, stats);
        bn_apply_f32<<<2048, 256, 0, stream>>>(out, stats, gamma, beta);
    } else {
        __hip_bfloat16* out_ws = (__hip_bfloat16*)d_ws;
        const size_t acc_elems = (size_t)N_OUT_PTS * C_CH;
        float* stats = (float*)((char*)d_ws + acc_elems * sizeof(__hip_bfloat16));
        const size_t clear_bytes = acc_elems * sizeof(__hip_bfloat16) + 2 * C_CH * sizeof(float);
        (void)hipMemsetAsync(d_ws, 0, clear_bytes, stream);
        scatter_gemm_fb<<<dim3(FB_BLKX, K_OFF), 256, 0, stream>>>(x, W, in_idx, out_idx, out_ws);
        bn_stats_fb<<<2048, 256, 0, stream>>>(out_ws, stats);
        bn_apply_fb<<<2048, 256, 0, stream>>>(out_ws, stats, gamma, beta, out);
    }
}

// Round 5
// 1174.419 us; speedup vs baseline: 1.0125x; 1.0125x over previous
//
#include <hip/hip_runtime.h>
#include <hip/hip_bf16.h>

// Problem constants (fixed by the reference file).
#define K_OFF 27
#define M_PTS 100000
#define KM (K_OFF * M_PTS)      // 2,700,000 contributions
#define C_CH 64
#define N_OUT_PTS 400000
#define BN_EPS 1e-5f
#define N_TILES (N_OUT_PTS / 16)   // 25000 output tiles of 16 rows
#define GBLOCKS (N_TILES / 4)      // 6250 gather blocks: 4 waves, 1 tile/wave
#define SRC_MASK 0x3FFFF           // entries pack (k<<18)|src, src<200000<2^18

typedef __attribute__((ext_vector_type(8))) short short8;  // 8 bf16 = 4 VGPRs
typedef __attribute__((ext_vector_type(4))) float f32x4;

__device__ inline short bf16c(float f) {
    return __builtin_bit_cast(short, __float2bfloat16(f));
}

// Packed 2xbf16 atomic add (fallback path only).
__device__ inline void pk_atomic_add_bf16(__hip_bfloat16* p, int bits) {
#if __has_builtin(__builtin_amdgcn_global_atomic_fadd_v2bf16)
    typedef short s2v __attribute__((ext_vector_type(2)));
    typedef __attribute__((address_space(1))) s2v* gp;
    s2v v;
    __builtin_memcpy(&v, &bits, 4);
    __builtin_amdgcn_global_atomic_fadd_v2bf16((gp)(unsigned long long)p, v);
#else
    asm volatile("global_atomic_pk_add_bf16 %0, %1, off"
                 :: "v"((unsigned long long)p), "v"(bits) : "memory");
#endif
}

__device__ inline unsigned bytesum(unsigned v) {
    return (v & 255u) + ((v >> 8) & 255u) + ((v >> 16) & 255u) + (v >> 24);
}

// ===========================================================================
// x fp32 -> bf16 copy (one pass; reuses dead hist+cursor ws region).
// Same __float2bfloat16 rounding as the previous inline cvt -> identical math.
// ===========================================================================
__global__ __launch_bounds__(256) void xconv(
    const float* __restrict__ x, unsigned short* __restrict__ x16)
{
    const size_t n = (size_t)200000 * C_CH / 8;   // 1.6M chunks of 8
    const size_t stride = (size_t)gridDim.x * blockDim.x;
    const float4* x4 = (const float4*)x;
    for (size_t i = (size_t)blockIdx.x * blockDim.x + threadIdx.x; i < n; i += stride) {
        float4 a = x4[2 * i], b = x4[2 * i + 1];
        short8 v;
        v[0] = bf16c(a.x); v[1] = bf16c(a.y); v[2] = bf16c(a.z); v[3] = bf16c(a.w);
        v[4] = bf16c(b.x); v[5] = bf16c(b.y); v[6] = bf16c(b.z); v[7] = bf16c(b.w);
        *(short8*)(x16 + i * 8) = v;
    }
}

// ===========================================================================
// CSR construction: per-(row,k) byte-packed histogram -> scan -> k-sorted fill
// hist/cursor layout: 8 uints per row; byte j of word w = count for k=4w+j.
// ===========================================================================

__global__ __launch_bounds__(256) void hist_kernel(
    const int* __restrict__ out_idx, unsigned* __restrict__ hist)
{
    int i = blockIdx.x * 256 + threadIdx.x;
    if (i >= KM) return;
    int row = out_idx[i];
    int k = i / M_PTS;
    atomicAdd(&hist[(size_t)row * 8 + (k >> 2)], 1u << (8 * (k & 3)));
}

__global__ __launch_bounds__(256) void scan_a(
    const unsigned* __restrict__ hist, int* __restrict__ partial,
    int* __restrict__ blockSums)
{
    __shared__ int sh[256];
    const int t = threadIdx.x, b = blockIdx.x;
    const int r0 = b * 1024 + t * 4;
    int cnt[4] = {0, 0, 0, 0};
    if (r0 < N_OUT_PTS) {
        #pragma unroll
        for (int u = 0; u < 4; ++u) {
            const uint4* hp = (const uint4*)(hist + (size_t)(r0 + u) * 8);
            uint4 a = hp[0], bq = hp[1];
            cnt[u] = (int)(bytesum(a.x) + bytesum(a.y) + bytesum(a.z) + bytesum(a.w) +
                           bytesum(bq.x) + bytesum(bq.y) + bytesum(bq.z) + bytesum(bq.w));
        }
    }
    int tsum = cnt[0] + cnt[1] + cnt[2] + cnt[3];
    sh[t] = tsum;
    __syncthreads();
    for (int o = 1; o < 256; o <<= 1) {
        int u = (t >= o) ? sh[t - o] : 0;
        __syncthreads();
        sh[t] += u;
        __syncthreads();
    }
    int excl = sh[t] - tsum;
    if (r0 < N_OUT_PTS) {
        partial[r0]     = excl;
        partial[r0 + 1] = excl + cnt[0];
        partial[r0 + 2] = excl + cnt[0] + cnt[1];
        partial[r0 + 3] = excl + cnt[0] + cnt[1] + cnt[2];
    }
    if (t == 255) blockSums[b] = sh[255];
}

#define SCAN_BLOCKS ((N_OUT_PTS + 1023) / 1024)   // 391

__global__ __launch_bounds__(512) void scan_b(
    const int* __restrict__ blockSums, int* __restrict__ blockOff)
{
    __shared__ int sh[512];
    const int t = threadIdx.x;
    int v = (t < SCAN_BLOCKS) ? blockSums[t] : 0;
    sh[t] = v;
    __syncthreads();
    for (int o = 1; o < 512; o <<= 1) {
        int u = (t >= o) ? sh[t - o] : 0;
        __syncthreads();
        sh[t] += u;
        __syncthreads();
    }
    if (t < SCAN_BLOCKS) blockOff[t] = sh[t] - v;
}

// Place each contribution at row_start + (#entries of row with k'<k) + seq-in-k.
// Entry value packs (k<<18)|src so the gather never touches hist.
__global__ __launch_bounds__(256) void fill_kernel(
    const int* __restrict__ out_idx, const int* __restrict__ in_idx,
    const unsigned* __restrict__ hist, unsigned* __restrict__ cursor,
    const int* __restrict__ partial, const int* __restrict__ blockOff,
    int* __restrict__ entries)
{
    int i = blockIdx.x * 256 + threadIdx.x;
    if (i >= KM) return;
    int row = out_idx[i];
    int k = i / M_PTS;
    const unsigned* hw = hist + (size_t)row * 8;
    int w = k >> 2, r = k & 3;
    int pre = 0;
    for (int q = 0; q < w; ++q) pre += (int)bytesum(hw[q]);
    unsigned v = hw[w];
    for (int b = 0; b < r; ++b) pre += (int)((v >> (8 * b)) & 255u);
    unsigned old = atomicAdd(&cursor[(size_t)row * 8 + w], 1u << (8 * r));
    int inK = (int)((old >> (8 * r)) & 255u);
    int pos = partial[row] + blockOff[row >> 10] + pre + inK;
    entries[pos] = (k << 18) | in_idx[i];
}

// Prepack W into per-lane MFMA B-fragment layout: packedB[k][lane][s*4+tt][j],
// element j = bf16(W[k][32s+8g+j][4c+tt]). 221 KB, L2-resident.
__global__ __launch_bounds__(64) void prepack_B(
    const float* __restrict__ W, unsigned short* __restrict__ packedB)
{
    const int k = blockIdx.x;
    const int lane = threadIdx.x;
    const int g = lane >> 4, c = lane & 15;
    const float* __restrict__ Wk = W + (size_t)k * C_CH * C_CH;
    #pragma unroll
    for (int s = 0; s < 2; ++s) {
        #pragma unroll
        for (int tt = 0; tt < 4; ++tt) {
            short8 v;
            #pragma unroll
            for (int j = 0; j < 8; ++j)
                v[j] = bf16c(Wk[(size_t)(32 * s + 8 * g + j) * C_CH + 4 * c + tt]);
            *(short8*)(packedB + ((size_t)(k * 64 + lane)) * 64 + (s * 4 + tt) * 8) = v;
        }
    }
}

// ===========================================================================
// Output-stationary fused gather-GEMM. One wave = 1 tile of 16 rows.
// Lane (g,c): stream-role row = tile*16+c; write-role rows = tile*16+4g+e,
// couts 4c+tt (D layout verified in rounds 1/4). Entries pack (k<<18)|src and
// are k-sorted per row, so each lane consumes one FLAT stream across the k
// loop. Two-level depth-2 software pipeline (ids + bf16 x-rows) with static
// register shifts keeps ~2 rounds of latency hiding on both load levels.
// ===========================================================================
__global__ __launch_bounds__(256, 4) void gather_bn_fused(
    const unsigned short* __restrict__ x16,
    const unsigned short* __restrict__ packedB,
    const int* __restrict__ entries, const int* __restrict__ partial,
    const int* __restrict__ blockOff,
    float* __restrict__ preact, float* __restrict__ pstats)
{
    const int lane = threadIdx.x & 63;
    const int wave = threadIdx.x >> 6;
    const int g = lane >> 4, c = lane & 15;
    const int tile = blockIdx.x * 4 + wave;   // 0..24999
    const int row = tile * 16 + c;

    int ptr = partial[row] + blockOff[row >> 10];
    int end;
    if (row == N_OUT_PTS - 1) end = KM;
    else end = partial[row + 1] + blockOff[(row + 1) >> 10];

    // id pipeline depth 3, x pipeline depth 2. entries has a zeroed 64-int
    // pad past KM (ptr+2 <= KM+2), so overrun reads decode to k=0/src=0 and
    // are never consumed (ptr >= end gates activity).
    int id0 = entries[ptr];
    int id1 = entries[ptr + 1];
    int id2 = entries[ptr + 2];

    const unsigned short* __restrict__ x0 = x16 + 8 * g;        // af0 slice base
    const unsigned short* __restrict__ x1 = x16 + 32 + 8 * g;   // af1 slice base

    short8 xa0 = *(const short8*)(x0 + (size_t)(id0 & SRC_MASK) * C_CH);
    short8 xb0 = *(const short8*)(x1 + (size_t)(id0 & SRC_MASK) * C_CH);
    short8 xa1 = *(const short8*)(x0 + (size_t)(id1 & SRC_MASK) * C_CH);
    short8 xb1 = *(const short8*)(x1 + (size_t)(id1 & SRC_MASK) * C_CH);

    const short8 zero8 = {0, 0, 0, 0, 0, 0, 0, 0};
    f32x4 acc[4];
    #pragma unroll
    for (int tt = 0; tt < 4; ++tt) acc[tt] = (f32x4){0.f, 0.f, 0.f, 0.f};

    for (int k = 0; k < K_OFF; ++k) {
        short8 bfrag[8];   // [s*4+tt]
        {
            const short8* bp = (const short8*)packedB + (size_t)(k * 64 + lane) * 8;
            #pragma unroll
            for (int f = 0; f < 8; ++f) bfrag[f] = bp[f];
        }
        while (__any(ptr < end && (id0 >> 18) == k)) {
            bool act = (ptr < end) && ((id0 >> 18) == k);
            short8 af0 = act ? xa0 : zero8;
            short8 af1 = act ? xb0 : zero8;
            if (act) {
                // advance both pipelines (exec-masked: inactive lanes freeze)
                xa0 = xa1; xb0 = xb1;
                const size_t s2 = (size_t)(id2 & SRC_MASK) * C_CH;
                xa1 = *(const short8*)(x0 + s2);
                xb1 = *(const short8*)(x1 + s2);
                id0 = id1; id1 = id2;
                ++ptr;
                id2 = entries[ptr + 2];
            }
            #pragma unroll
            for (int tt = 0; tt < 4; ++tt) {
                f32x4 z = __builtin_amdgcn_mfma_f32_16x16x32_bf16(af0, bfrag[tt], acc[tt], 0, 0, 0);
                acc[tt] = __builtin_amdgcn_mfma_f32_16x16x32_bf16(af1, bfrag[4 + tt], z, 0, 0, 0);
            }
        }
    }

    // Epilogue: coalesced preact writes + per-block BN partial sums (NO
    // global atomics: 800K same-address f32 atomics replaced by pstats).
    float s[4] = {0.f, 0.f, 0.f, 0.f}, q[4] = {0.f, 0.f, 0.f, 0.f};
    #pragma unroll
    for (int e = 0; e < 4; ++e) {
        float4 w;
        w.x = acc[0][e]; w.y = acc[1][e]; w.z = acc[2][e]; w.w = acc[3][e];
        *(float4*)(preact + (size_t)(tile * 16 + 4 * g + e) * C_CH + 4 * c) = w;
        s[0] += w.x; s[1] += w.y; s[2] += w.z; s[3] += w.w;
        q[0] += w.x * w.x; q[1] += w.y * w.y; q[2] += w.z * w.z; q[3] += w.w * w.w;
    }

    __shared__ float sh[2][256][4];
    #pragma unroll
    for (int tt = 0; tt < 4; ++tt) {
        sh[0][threadIdx.x][tt] = s[tt];
        sh[1][threadIdx.x][tt] = q[tt];
    }
    __syncthreads();
    if (threadIdx.x < C_CH) {
        const int ch = threadIdx.x;
        const int cc = ch >> 2, jj = ch & 3;
        float ts = 0.f, tq = 0.f;
        #pragma unroll
        for (int u = 0; u < 16; ++u) {
            ts += sh[0][16 * u + cc][jj];
            tq += sh[1][16 * u + cc][jj];
        }
        pstats[(size_t)blockIdx.x * 128 + ch] = ts;
        pstats[(size_t)blockIdx.x * 128 + C_CH + ch] = tq;
    }
}

// Reduce per-block BN partials: block b owns stats slot b (128 slots).
__global__ __launch_bounds__(256) void stats_reduce(
    const float* __restrict__ pstats, float* __restrict__ stats)
{
    const int b = blockIdx.x;   // 0..127
    float s = 0.f;
    for (int i = threadIdx.x; i < GBLOCKS; i += 256)
        s += pstats[(size_t)i * 128 + b];
    __shared__ float sh[256];
    sh[threadIdx.x] = s;
    __syncthreads();
    for (int o = 128; o > 0; o >>= 1) {
        if (threadIdx.x < o) sh[threadIdx.x] += sh[threadIdx.x + o];
        __syncthreads();
    }
    if (threadIdx.x == 0) stats[b] = sh[0];
}

// In-place BN+ReLU on fp32 preact (= d_out).
__global__ __launch_bounds__(256) void bn_apply_f32(
    float* __restrict__ out, const float* __restrict__ stats,
    const float* __restrict__ gamma, const float* __restrict__ beta)
{
    const float inv_n = 1.0f / (float)N_OUT_PTS;
    const int c0 = 8 * (threadIdx.x & 7);
    float sc[8], bs[8];
    #pragma unroll
    for (int j = 0; j < 8; ++j) {
        int ch = c0 + j;
        float mean = stats[ch] * inv_n;
        float var = stats[C_CH + ch] * inv_n - mean * mean;
        float sfac = gamma[ch] * rsqrtf(var + BN_EPS);
        sc[j] = sfac;
        bs[j] = beta[ch] - mean * sfac;
    }
    float4* o4 = (float4*)out;
    const size_t n = (size_t)N_OUT_PTS * C_CH / 8;
    const size_t stride = (size_t)gridDim.x * blockDim.x;
    for (size_t i = (size_t)blockIdx.x * blockDim.x + threadIdx.x; i < n; i += stride) {
        float4 r0 = o4[2 * i], r1 = o4[2 * i + 1];
        r0.x = fmaxf(fmaf(r0.x, sc[0], bs[0]), 0.f);
        r0.y = fmaxf(fmaf(r0.y, sc[1], bs[1]), 0.f);
        r0.z = fmaxf(fmaf(r0.z, sc[2], bs[2]), 0.f);
        r0.w = fmaxf(fmaf(r0.w, sc[3], bs[3]), 0.f);
        r1.x = fmaxf(fmaf(r1.x, sc[4], bs[4]), 0.f);
        r1.y = fmaxf(fmaf(r1.y, sc[5], bs[5]), 0.f);
        r1.z = fmaxf(fmaf(r1.z, sc[6], bs[6]), 0.f);
        r1.w = fmaxf(fmaf(r1.w, sc[7], bs[7]), 0.f);
        o4[2 * i] = r0;
        o4[2 * i + 1] = r1;
    }
}

// ===========================================================================
// FALLBACK (ws implausibly small): atomic-scatter pipeline, proven pass.
// ===========================================================================
#define TILE_PTS 16
#define NT (M_PTS / TILE_PTS)
#define FB_BLKX 64
#define FB_WSTRIDE (FB_BLKX * 4)

__global__ __launch_bounds__(256, 4) void scatter_gemm_fb(
    const float* __restrict__ x, const float* __restrict__ W,
    const int* __restrict__ in_idx, const int* __restrict__ out_idx,
    __hip_bfloat16* __restrict__ out_ws)
{
    const int k = blockIdx.y;
    const int lane = threadIdx.x & 63;
    const int wave = threadIdx.x >> 6;
    const int g = lane >> 4, c = lane & 15;
    short8 bfrag[2][4];
    {
        const float* __restrict__ Wk = W + (size_t)k * C_CH * C_CH;
        #pragma unroll
        for (int s = 0; s < 2; ++s)
            #pragma unroll
            for (int tt = 0; tt < 4; ++tt) {
                short8 v;
                #pragma unroll
                for (int j = 0; j < 8; ++j)
                    v[j] = bf16c(Wk[(size_t)(32 * s + 8 * g + j) * C_CH + 4 * c + tt]);
                bfrag[s][tt] = v;
            }
    }
    const int kbase = k * M_PTS;
    for (int t = blockIdx.x * 4 + wave; t < NT; t += FB_WSTRIDE) {
        int src = in_idx[kbase + t * TILE_PTS + c];
        const float4* xr = (const float4*)x + (size_t)src * 16;
        float4 cur[4];
        cur[0] = xr[2 * g];     cur[1] = xr[2 * g + 1];
        cur[2] = xr[8 + 2 * g]; cur[3] = xr[8 + 2 * g + 1];
        int dstv[4];
        #pragma unroll
        for (int e = 0; e < 4; ++e)
            dstv[e] = out_idx[kbase + t * TILE_PTS + 4 * g + e];
        short8 af0, af1;
        #pragma unroll
        for (int j = 0; j < 4; ++j) {
            af0[j] = bf16c(cur[0][j]); af0[j + 4] = bf16c(cur[1][j]);
            af1[j] = bf16c(cur[2][j]); af1[j + 4] = bf16c(cur[3][j]);
        }
        f32x4 acc[4];
        #pragma unroll
        for (int tt = 0; tt < 4; ++tt) {
            f32x4 z = {0.f, 0.f, 0.f, 0.f};
            z       = __builtin_amdgcn_mfma_f32_16x16x32_bf16(af0, bfrag[0][tt], z, 0, 0, 0);
            acc[tt] = __builtin_amdgcn_mfma_f32_16x16x32_bf16(af1, bfrag[1][tt], z, 0, 0, 0);
        }
        #pragma unroll
        for (int e = 0; e < 4; ++e) {
            __hip_bfloat16* rp = out_ws + (size_t)dstv[e] * C_CH + 4 * c;
            union { __hip_bfloat162 h; int i; } p0, p1;
            p0.h = __hip_bfloat162(__float2bfloat16(acc[0][e]), __float2bfloat16(acc[1][e]));
            p1.h = __hip_bfloat162(__float2bfloat16(acc[2][e]), __float2bfloat16(acc[3][e]));
            pk_atomic_add_bf16(rp, p0.i);
            pk_atomic_add_bf16(rp + 2, p1.i);
        }
    }
}

__global__ __launch_bounds__(256) void bn_stats_fb(
    const __hip_bfloat16* __restrict__ ws, float* __restrict__ stats)
{
    const uint4* in = (const uint4*)ws;
    const size_t n = (size_t)N_OUT_PTS * C_CH / 8;
    const size_t stride = (size_t)gridDim.x * blockDim.x;
    float s[8], s2[8];
    #pragma unroll
    for (int j = 0; j < 8; ++j) { s[j] = 0.f; s2[j] = 0.f; }
    for (size_t i = (size_t)blockIdx.x * blockDim.x + threadIdx.x; i < n; i += stride) {
        uint4 qv = in[i];
        unsigned wds[4] = {qv.x, qv.y, qv.z, qv.w};
        #pragma unroll
        for (int j = 0; j < 4; ++j) {
            __hip_bfloat162 h = *(__hip_bfloat162*)&wds[j];
            float f0 = __low2float(h), f1 = __high2float(h);
            s[2 * j] += f0;  s2[2 * j] += f0 * f0;
            s[2 * j + 1] += f1; s2[2 * j + 1] += f1 * f1;
        }
    }
    __shared__ float sh[2][256][8];
    #pragma unroll
    for (int j = 0; j < 8; ++j) { sh[0][threadIdx.x][j] = s[j]; sh[1][threadIdx.x][j] = s2[j]; }
    __syncthreads();
    if (threadIdx.x < C_CH) {
        const int cch = threadIdx.x;
        float ts = 0.f, t2 = 0.f;
        #pragma unroll
        for (int u = 0; u < 32; ++u) {
            ts += sh[0][8 * u + (cch >> 3)][cch & 7];
            t2 += sh[1][8 * u + (cch >> 3)][cch & 7];
        }
        unsafeAtomicAdd(&stats[cch], ts);
        unsafeAtomicAdd(&stats[C_CH + cch], t2);
    }
}

__global__ __launch_bounds__(256) void bn_apply_fb(
    const __hip_bfloat16* __restrict__ ws, const float* __restrict__ stats,
    const float* __restrict__ gamma, const float* __restrict__ beta,
    float* __restrict__ out)
{
    const float inv_n = 1.0f / (float)N_OUT_PTS;
    const int c0 = 8 * (threadIdx.x & 7);
    float sc[8], bs[8];
    #pragma unroll
    for (int j = 0; j < 8; ++j) {
        int ch = c0 + j;
        float mean = stats[ch] * inv_n;
        float var = stats[C_CH + ch] * inv_n - mean * mean;
        float sfac = gamma[ch] * rsqrtf(var + BN_EPS);
        sc[j] = sfac;
        bs[j] = beta[ch] - mean * sfac;
    }
    const uint4* in = (const uint4*)ws;
    float4* o4 = (float4*)out;
    const size_t n = (size_t)N_OUT_PTS * C_CH / 8;
    const size_t stride = (size_t)gridDim.x * blockDim.x;
    for (size_t i = (size_t)blockIdx.x * blockDim.x + threadIdx.x; i < n; i += stride) {
        uint4 qv = in[i];
        unsigned wds[4] = {qv.x, qv.y, qv.z, qv.w};
        float f[8];
        #pragma unroll
        for (int j = 0; j < 4; ++j) {
            __hip_bfloat162 h = *(__hip_bfloat162*)&wds[j];
            f[2 * j] = __low2float(h);
            f[2 * j + 1] = __high2float(h);
        }
        float4 r0, r1;
        r0.x = fmaxf(fmaf(f[0], sc[0], bs[0]), 0.f);
        r0.y = fmaxf(fmaf(f[1], sc[1], bs[1]), 0.f);
        r0.z = fmaxf(fmaf(f[2], sc[2], bs[2]), 0.f);
        r0.w = fmaxf(fmaf(f[3], sc[3], bs[3]), 0.f);
        r1.x = fmaxf(fmaf(f[4], sc[4], bs[4]), 0.f);
        r1.y = fmaxf(fmaf(f[5], sc[5], bs[5]), 0.f);
        r1.z = fmaxf(fmaf(f[6], sc[6], bs[6]), 0.f);
        r1.w = fmaxf(fmaf(f[7], sc[7], bs[7]), 0.f);
        o4[2 * i] = r0;
        o4[2 * i + 1] = r1;
    }
}

extern "C" void kernel_launch(void* const* d_in, const int* in_sizes, int n_in,
                              void* d_out, int out_size, void* d_ws, size_t ws_size,
                              hipStream_t stream) {
    const float* x      = (const float*)d_in[0];
    const float* W      = (const float*)d_in[1];
    const float* gamma  = (const float*)d_in[2];
    const float* beta   = (const float*)d_in[3];
    const int*   in_idx = (const int*)d_in[4];
    const int*   out_idx= (const int*)d_in[5];
    float* out = (float*)d_out;

    // Workspace layout (~42 MB; ws >= 51.2 MB evidenced by prior sessions).
    // hist+cursor (25.6 MB) are DEAD after fill_kernel and are reused as the
    // bf16 x copy (exactly 25.6 MB) written by xconv before the gather.
    auto al = [](size_t v) { return (v + 255) & ~(size_t)255; };
    size_t off = 0;
    const size_t entries_off = off; off += al((size_t)(KM + 64) * 4);
    const size_t partial_off = off; off += al((size_t)N_OUT_PTS * 4);
    const size_t zero_start  = off;
    const size_t hist_off    = off; off += al((size_t)N_OUT_PTS * 32);
    const size_t cursor_off  = off; off += al((size_t)N_OUT_PTS * 32);
    const size_t bsum_off    = off; off += al(512 * 4);
    const size_t boff_off    = off; off += al(512 * 4);
    const size_t stats_off   = off; off += al(2 * C_CH * sizeof(float));
    const size_t zero_end    = off;
    const size_t pstats_off  = off; off += al((size_t)GBLOCKS * 128 * 4);
    const size_t packB_off   = off; off += al((size_t)K_OFF * 64 * 128);
    const size_t NEEDED = off;

    if (ws_size >= NEEDED) {
        char* wsb = (char*)d_ws;
        int*      entries = (int*)(wsb + entries_off);
        int*      partial = (int*)(wsb + partial_off);
        unsigned* hist    = (unsigned*)(wsb + hist_off);
        unsigned* cursor  = (unsigned*)(wsb + cursor_off);
        int*      bsum    = (int*)(wsb + bsum_off);
        int*      boff    = (int*)(wsb + boff_off);
        float*    stats   = (float*)(wsb + stats_off);
        float*    pstats  = (float*)(wsb + pstats_off);
        unsigned short* packB = (unsigned short*)(wsb + packB_off);
        unsigned short* x16   = (unsigned short*)(wsb + hist_off);  // reuse

        (void)hipMemsetAsync(wsb + zero_start, 0, zero_end - zero_start, stream);
        (void)hipMemsetAsync(entries + KM, 0, 64 * sizeof(int), stream);

        prepack_B<<<K_OFF, 64, 0, stream>>>(W, packB);
        hist_kernel<<<(KM + 255) / 256, 256, 0, stream>>>(out_idx, hist);
        scan_a<<<SCAN_BLOCKS, 256, 0, stream>>>(hist, partial, bsum);
        scan_b<<<1, 512, 0, stream>>>(bsum, boff);
        fill_kernel<<<(KM + 255) / 256, 256, 0, stream>>>(
            out_idx, in_idx, hist, cursor, partial, boff, entries);
        xconv<<<2048, 256, 0, stream>>>(x, x16);   // overwrites dead hist+cursor
        gather_bn_fused<<<GBLOCKS, 256, 0, stream>>>(
            x16, packB, entries, partial, boff, out, pstats);
        stats_reduce<<<128, 256, 0, stream>>>(pstats, stats);
        bn_apply_f32<<<2048, 256, 0, stream>>>(out, stats, gamma, beta);
    } else {
        __hip_bfloat16* out_ws = (__hip_bfloat16*)d_ws;
        const size_t acc_elems = (size_t)N_OUT_PTS * C_CH;
        float* stats = (float*)((char*)d_ws + acc_elems * sizeof(__hip_bfloat16));
        const size_t clear_bytes = acc_elems * sizeof(__hip_bfloat16) + 2 * C_CH * sizeof(float);
        (void)hipMemsetAsync(d_ws, 0, clear_bytes, stream);
        scatter_gemm_fb<<<dim3(FB_BLKX, K_OFF), 256, 0, stream>>>(x, W, in_idx, out_idx, out_ws);
        bn_stats_fb<<<2048, 256, 0, stream>>>(out_ws, stats);
        bn_apply_fb<<<2048, 256, 0, stream>>>(out_ws, stats, gamma, beta, out);
    }
}